// Round 10
// baseline (2931.967 us; speedup 1.0000x reference)
//
#include <hip/hip_runtime.h>
#include <hip/hip_bf16.h>
#include <math.h>

// Problem dims
#define PP 400
#define QQ 30
#define BB 32
#define EE 300
#define HH 300
#define FF 300
#define AA 30
#define LL 2

typedef unsigned short ushort_t;
typedef unsigned int uint_t;
typedef __attribute__((ext_vector_type(8))) short short8;
typedef __attribute__((ext_vector_type(16))) float floatx16;
typedef __attribute__((ext_vector_type(4))) uint_t uintx4;

__device__ __forceinline__ uint_t f2bf(float f) {
    uint_t u = __float_as_uint(f);
    return (u + 0x7fffu + ((u >> 16) & 1u)) >> 16;
}
__device__ __forceinline__ float bf2f(ushort_t v) {
    return __uint_as_float(((uint_t)v) << 16);
}

// fast transcendentals (v_exp_f32 / v_rcp_f32; rel err ~1e-6 << bf16's 4e-3)
__device__ __forceinline__ float fast_sigmoid(float x) {
    float e = __builtin_amdgcn_exp2f(x * -1.44269504f);
    return __builtin_amdgcn_rcpf(1.f + e);
}
__device__ __forceinline__ float fast_tanh(float x) {
    float xc = fminf(15.f, fmaxf(-15.f, x));
    float e = __builtin_amdgcn_exp2f(xc * 2.88539008f);   // e^(2x)
    return (e - 1.f) * __builtin_amdgcn_rcpf(e + 1.f);
}

// ---------------------------------------------------------------------------
// Embedding gather -> bf16 with K padded 300->304 (pad zeroed)
__global__ void gather_embed_bf(const int* __restrict__ tok,
                                const float* __restrict__ embed,
                                ushort_t* __restrict__ out, int n_tok) {
    int i = blockIdx.x * blockDim.x + threadIdx.x;
    int n = n_tok * 304;
    if (i >= n) return;
    int row = i / 304, e = i - row * 304;
    out[i] = (e < EE) ? (ushort_t)f2bf(embed[(size_t)tok[row] * EE + e]) : 0;
}

// fp32 [R][K] -> bf16 [R][KP], zero pad
__global__ void convert_pad_bf16(const float* __restrict__ src,
                                 ushort_t* __restrict__ dst,
                                 int R, int K, int KP) {
    int i = blockIdx.x * blockDim.x + threadIdx.x;
    if (i >= R * KP) return;
    int r = i / KP, k = i - r * KP;
    dst[i] = (k < K) ? (ushort_t)f2bf(src[(size_t)r * K + k]) : 0;
}

// ---------------------------------------------------------------------------
// MFMA bf16 GEMM: C[M,N] = A[M,KP] @ B[N,KP]^T + bias[N], optional relu.
__global__ __launch_bounds__(256) void gemm_bf16_nt(
        const ushort_t* __restrict__ A, const ushort_t* __restrict__ B,
        const float* __restrict__ bias, float* __restrict__ C,
        int M, int N, int KP, int relu) {
    __shared__ __align__(16) ushort_t As[64][16];
    __shared__ __align__(16) ushort_t Bs[64][16];
    int tid = threadIdx.x;
    int m0 = blockIdx.y * 64, n0 = blockIdx.x * 64;
    int lane = tid & 63, wv = tid >> 6;
    int wm = wv >> 1, wn = wv & 1;
    int tile = tid >> 7;
    int trow = (tid & 127) >> 1;
    int tkof = (tid & 1) * 8;
    floatx16 acc;
    #pragma unroll
    for (int r = 0; r < 16; r++) acc[r] = 0.f;

    for (int k0 = 0; k0 < KP; k0 += 16) {
        short8 v;
        if (tile == 0) {
            v = *(const short8*)(A + (size_t)(m0 + trow) * KP + k0 + tkof);
        } else {
            int br = n0 + trow;
            if (br < N)
                v = *(const short8*)(B + (size_t)br * KP + k0 + tkof);
            else
                v = short8(0);
        }
        __syncthreads();
        if (tile == 0) *(short8*)&As[trow][tkof] = v;
        else           *(short8*)&Bs[trow][tkof] = v;
        __syncthreads();
        short8 af = *(const short8*)&As[wm * 32 + (lane & 31)][(lane >> 5) * 8];
        short8 bf = *(const short8*)&Bs[wn * 32 + (lane & 31)][(lane >> 5) * 8];
        acc = __builtin_amdgcn_mfma_f32_32x32x16_bf16(af, bf, acc, 0, 0, 0);
    }
    int col = n0 + wn * 32 + (lane & 31);
    if (col < N) {
        float bv = bias[col];
        int rbase = m0 + wm * 32 + 4 * (lane >> 5);
        #pragma unroll
        for (int r = 0; r < 16; r++) {
            int row = rbase + (r & 3) + 8 * (r >> 2);
            float v = acc[r] + bv;
            if (relu) v = fmaxf(v, 0.f);
            C[(size_t)row * N + col] = v;
        }
    }
}

// ---------------------------------------------------------------------------
__global__ void scores_softmax(const float* __restrict__ ffp,
                               const float* __restrict__ ffq,
                               const float* __restrict__ p_mask,
                               const float* __restrict__ q_mask,
                               float* __restrict__ weights) {
    int blk = blockIdx.x;          // p*BB + b
    int p = blk / BB, b = blk - p * BB;
    __shared__ float fp[FF];
    __shared__ float sq[QQ];
    for (int f = threadIdx.x; f < FF; f += blockDim.x)
        fp[f] = ffp[(size_t)(p * BB + b) * FF + f];
    __syncthreads();
    int q = threadIdx.x;
    if (q < QQ) {
        const float* fq = ffq + (size_t)(q * BB + b) * FF;
        float s = 0.f;
        for (int f = 0; f < FF; f++) s += fp[f] * fq[f];
        s *= p_mask[p * BB + b] * q_mask[q * BB + b];
        sq[q] = s;
    }
    __syncthreads();
    if (q < QQ) {
        float m = -INFINITY;
        for (int k = 0; k < QQ; k++) m = fmaxf(m, sq[k]);
        float sum = 0.f;
        for (int k = 0; k < QQ; k++) sum += expf(sq[k] - m);
        weights[(size_t)b * PP * QQ + p * QQ + q] = expf(sq[q] - m) / sum;
    }
}

// ---------------------------------------------------------------------------
__global__ void align_concat_bf(const float* __restrict__ weights,
                                const ushort_t* __restrict__ q_embBF,
                                const ushort_t* __restrict__ p_embBF,
                                ushort_t* __restrict__ x0BF) {
    int blk = blockIdx.x;          // p*BB + b
    int p = blk / BB, b = blk - p * BB;
    __shared__ float w[QQ];
    if (threadIdx.x < QQ)
        w[threadIdx.x] = weights[(size_t)b * PP * QQ + p * QQ + threadIdx.x];
    __syncthreads();
    size_t obase = (size_t)(p * BB + b) * 608;
    for (int e = threadIdx.x; e < EE; e += blockDim.x) {
        float acc = 0.f;
        for (int q = 0; q < QQ; q++)
            acc += w[q] * bf2f(q_embBF[(size_t)(q * BB + b) * 304 + e]);
        x0BF[obase + e] = p_embBF[(size_t)(p * BB + b) * 304 + e];
        x0BF[obase + EE + e] = (ushort_t)f2bf(acc);
    }
}

// ---------------------------------------------------------------------------
// w_hh fp32 [4][900][300] -> bf16 (RNE) same layout (GRU A-fragments)
__global__ void convert_whh_bf16(const float* __restrict__ w,
                                 ushort_t* __restrict__ o) {
    int i = blockIdx.x * blockDim.x + threadIdx.x;
    if (i >= 4 * 900 * 300) return;
    o[i] = (ushort_t)f2bf(w[i]);
}

// ---------------------------------------------------------------------------
// Persistent BiGRU layer, MFMA recurrence, tagged-packet handoff.
// R18 = R17 with ONE reorder: the `out` store is issued BEFORE the vmcnt(0)
// drain (concurrent completion with the packet store) instead of after it.
// In R17 the out store sat outstanding in waves 0-4's VMEM FIFO across the
// loop edge, so the next step's first vmcnt(3) poll check waited ~600-900cy
// for it to complete. Now every wave enters the poll with an empty FIFO.
#define GRP 5
#define RSLOT 8
#define NPKT 1600            // per dir: 300 j * 32 b / 6
#define HBUF_DWORDS (2 * RSLOT * NPKT * 4)

__global__ __launch_bounds__(512, 1) void gru_layer(
        const float* __restrict__ xp_all, // [2 dir][400][32][900] contiguous
        const ushort_t* __restrict__ wbf, // [2 dir][900][300] bf16, this layer
        const float* __restrict__ bhh,    // [2 dir][900], this layer
        uint_t* __restrict__ hbuf,        // shared packet ring (zeroed)
        int layer,
        ushort_t* __restrict__ out) {     // [400][32][608] bf16
    int dir = blockIdx.x / GRP;
    int bi  = blockIdx.x - dir * GRP;
    int j0  = bi * 60;
    const float* xp = xp_all + (size_t)dir * (400 * 32 * 900);
    int tid = threadIdx.x;
    int lane = tid & 63;
    int wv = tid >> 6;                 // wave 0..7 (0-5 do MFMA)
    uint_t* hb_dir = hbuf + (size_t)dir * (RSLOT * NPKT * 4);

    __shared__ __align__(16) ushort_t sh2[32][312]; // h bf16 [batch][k]
    __shared__ float sgh[180][33];    // gh f32 [block row][batch]

    for (int i = tid; i < 32 * 156; i += 512) ((uint_t*)sh2)[i] = 0u;

    // A-fragments resident: wave wv owns block rows wv*32 .. +31
    short8 afrag[19];
    if (wv < 6) {
        int m = lane & 31, half = lane >> 5;
        int r = wv * 32 + m;
        if (r < 180) {
            int g = r / 60, jl = r - g * 60;
            const ushort_t* wrow = wbf + (size_t)dir * 270000
                                   + (size_t)(g * 300 + j0 + jl) * 300;
            for (int c = 0; c < 19; c++) {
                int k0 = c * 16 + half * 8;
                short8 f;
                #pragma unroll
                for (int e = 0; e < 8; e++) {
                    int k = k0 + e;
                    f[e] = (short)((k < 300) ? wrow[k] : (ushort_t)0);
                }
                afrag[c] = f;
            }
        } else {
            #pragma unroll
            for (int c = 0; c < 19; c++) afrag[c] = short8(0);
        }
    }

    // poll assignment: pad to exactly 4 packets/thread (uniform vmcnt
    // immediates); own block's packets skipped (producers write them
    // straight into next-step sh2). Every thread has >=2 real packets.
    int pollP[4], polldst[4];
    int npoll = 0;
    int ownlo = bi * 320;
    for (int k = 0; k < 4; k++) {
        int P = tid + 512 * k;
        if (P < NPKT && (P < ownlo || P >= ownlo + 320)) {
            pollP[npoll] = P;
            int pbi = P / 320, rem = P - pbi * 320;
            int pb = rem / 10, pq = rem - pb * 10;
            polldst[npoll] = pb * 156 + pbi * 30 + 3 * pq;
            npoll++;
        }
    }
    for (int k = npoll; k < 4; k++) { pollP[k] = pollP[0]; polldst[k] = polldst[0]; }

    // gate ownership (t<320): b=t/10, q=t%10 -> h[j0+6q..+5] of batch b
    int gb = tid / 10, gq = tid - (tid / 10) * 10;
    float hprev[6] = {0.f, 0.f, 0.f, 0.f, 0.f, 0.f};
    float br_[6], bz_[6], bn_[6];
    if (tid < 320) {
        #pragma unroll
        for (int i = 0; i < 6; i++) {
            int jj = j0 + gq * 6 + i;
            br_[i] = bhh[dir * 900 + jj];
            bz_[i] = bhh[dir * 900 + 300 + jj];
            bn_[i] = bhh[dir * 900 + 600 + jj];
        }
    }
    __syncthreads();

    for (int s = 0; s < PP; s++) {
        int te = dir ? (PP - 1 - s) : s;
        // poll tagged packets for h(s); unpack into sh2 (FIFO is empty:
        // both stores of the previous step were drained before loop edge)
        if (s > 0) {
            uint_t want = (uint_t)(layer * 1024 + s);
            const uint_t* base = hb_dir + (size_t)(s & 7) * (NPKT * 4);
            const uint_t* a0p = base + (size_t)pollP[0] * 4;
            const uint_t* a1p = base + (size_t)pollP[1] * 4;
            const uint_t* a2p = base + (size_t)pollP[2] * 4;
            const uint_t* a3p = base + (size_t)pollP[3] * 4;
            int pend = (1 << npoll) - 1;
            uint_t* shdw = (uint_t*)sh2;
            while (pend) {
                uintx4 v0, v1, v2, v3;
                asm volatile("global_load_dwordx4 %0, %1, off sc0 sc1"
                             : "=&v"(v0) : "v"(a0p) : "memory");
                asm volatile("global_load_dwordx4 %0, %1, off sc0 sc1"
                             : "=&v"(v1) : "v"(a1p) : "memory");
                asm volatile("global_load_dwordx4 %0, %1, off sc0 sc1"
                             : "=&v"(v2) : "v"(a2p) : "memory");
                asm volatile("global_load_dwordx4 %0, %1, off sc0 sc1"
                             : "=&v"(v3) : "v"(a3p) : "memory");
                asm volatile("s_waitcnt vmcnt(3)" ::: "memory");
                __builtin_amdgcn_sched_barrier(0);
                if ((pend & 1) && v0.w == want) {
                    pend &= ~1;
                    shdw[polldst[0] + 0] = v0.x;
                    shdw[polldst[0] + 1] = v0.y;
                    shdw[polldst[0] + 2] = v0.z;
                }
                asm volatile("s_waitcnt vmcnt(2)" ::: "memory");
                __builtin_amdgcn_sched_barrier(0);
                if ((pend & 2) && v1.w == want) {
                    pend &= ~2;
                    shdw[polldst[1] + 0] = v1.x;
                    shdw[polldst[1] + 1] = v1.y;
                    shdw[polldst[1] + 2] = v1.z;
                }
                asm volatile("s_waitcnt vmcnt(1)" ::: "memory");
                __builtin_amdgcn_sched_barrier(0);
                if ((pend & 4) && v2.w == want) {
                    pend &= ~4;
                    shdw[polldst[2] + 0] = v2.x;
                    shdw[polldst[2] + 1] = v2.y;
                    shdw[polldst[2] + 2] = v2.z;
                }
                asm volatile("s_waitcnt vmcnt(0)" ::: "memory");
                __builtin_amdgcn_sched_barrier(0);
                if ((pend & 8) && v3.w == want) {
                    pend &= ~8;
                    shdw[polldst[3] + 0] = v3.x;
                    shdw[polldst[3] + 1] = v3.y;
                    shdw[polldst[3] + 2] = v3.z;
                }
            }
        }
        // xp prefetch — after the poll (R17): latency hides under MFMA phase
        float xrv[6], xzv[6], xnv[6];
        if (tid < 320) {
            const float* base = xp + ((size_t)te * 32 + gb) * 900 + j0 + gq * 6;
            #pragma unroll
            for (int u = 0; u < 3; u++) {
                *(float2*)&xrv[2 * u] = *(const float2*)(base + 2 * u);
                *(float2*)&xzv[2 * u] = *(const float2*)(base + 300 + 2 * u);
                *(float2*)&xnv[2 * u] = *(const float2*)(base + 600 + 2 * u);
            }
        }
        __syncthreads();                       // B1: sh2 complete
        // MFMA: waves 0-5, A resident, B from LDS; 2 independent acc chains
        if (wv < 6) {
            floatx16 a0, a1;
            #pragma unroll
            for (int r = 0; r < 16; r++) { a0[r] = 0.f; a1[r] = 0.f; }
            int n = lane & 31, half = lane >> 5;
            #pragma unroll
            for (int c = 0; c < 18; c += 2) {
                short8 bf0 = *(const short8*)&sh2[n][c * 16 + half * 8];
                a0 = __builtin_amdgcn_mfma_f32_32x32x16_bf16(
                    afrag[c], bf0, a0, 0, 0, 0);
                short8 bf1 = *(const short8*)&sh2[n][(c + 1) * 16 + half * 8];
                a1 = __builtin_amdgcn_mfma_f32_32x32x16_bf16(
                    afrag[c + 1], bf1, a1, 0, 0, 0);
            }
            {
                short8 bf0 = *(const short8*)&sh2[n][18 * 16 + half * 8];
                a0 = __builtin_amdgcn_mfma_f32_32x32x16_bf16(
                    afrag[18], bf0, a0, 0, 0, 0);
            }
            int col = lane & 31, rbase = 4 * (lane >> 5);
            #pragma unroll
            for (int r = 0; r < 16; r++) {
                int row = (r & 3) + 8 * (r >> 2) + rbase;
                int grow = wv * 32 + row;
                if (grow < 180) sgh[grow][col] = a0[r] + a1[r];
            }
        }
        __syncthreads();                       // B2: sgh complete
        // gates from registers; publish packet straight from registers
        if (tid < 320) {
            float houts[6];
            uint_t pk[3];
            #pragma unroll
            for (int i = 0; i < 6; i++) {
                int jl = gq * 6 + i;
                float ghr = sgh[jl][gb];
                float ghz = sgh[60 + jl][gb];
                float ghn = sgh[120 + jl][gb];
                float r = fast_sigmoid(xrv[i] + ghr + br_[i]);
                float z = fast_sigmoid(xzv[i] + ghz + bz_[i]);
                float n = fast_tanh(xnv[i] + r * (ghn + bn_[i]));
                float h = (1.f - z) * n + z * hprev[i];
                hprev[i] = h;
                houts[i] = h;
            }
            #pragma unroll
            for (int u = 0; u < 3; u++)
                pk[u] = f2bf(houts[2 * u]) | (f2bf(houts[2 * u + 1]) << 16);
            uintx4 pkt;
            pkt.x = pk[0]; pkt.y = pk[1]; pkt.z = pk[2];
            pkt.w = (uint_t)(layer * 1024 + s + 1);
            uint_t* pa = hb_dir + (size_t)((s + 1) & 7) * (NPKT * 4)
                         + (size_t)(bi * 320 + tid) * 4;
            asm volatile("global_store_dwordx4 %0, %1, off sc0 sc1"
                         :: "v"(pa), "v"(pkt) : "memory");
            // bf16 out store issued BEFORE the drain (R18): completes
            // concurrently with the packet store; poll FIFO stays empty.
            uint_t* ob = (uint_t*)(out + ((size_t)te * 32 + gb) * 608
                                   + dir * 300 + j0 + gq * 6);
            ob[0] = pk[0]; ob[1] = pk[1]; ob[2] = pk[2];
            // single drain covers both stores: packet visibility starts now,
            // and the next poll round's vmcnt checks see an empty FIFO.
            asm volatile("s_waitcnt vmcnt(0)" ::: "memory");
            __builtin_amdgcn_sched_barrier(0);
            // own-block h for next step goes straight into LDS (no self RT).
            {
                uint_t* shdw2 = (uint_t*)sh2;
                int own = gb * 156 + bi * 30 + 3 * gq;
                shdw2[own + 0] = pk[0];
                shdw2[own + 1] = pk[1];
                shdw2[own + 2] = pk[2];
            }
        }
    }
}

// ---------------------------------------------------------------------------
__global__ void span_score(const float* __restrict__ stt,
                           const float* __restrict__ endv,
                           const float* __restrict__ w_a,
                           const int* __restrict__ p_lens,
                           float* __restrict__ final_) {
    int blk = blockIdx.x;          // p*BB + b
    int p = blk / BB, b = blk - p * BB;
    __shared__ float ss[FF];
    __shared__ float wa[FF];
    for (int f = threadIdx.x; f < FF; f += blockDim.x) {
        ss[f] = stt[(size_t)(p * BB + b) * FF + f];
        wa[f] = w_a[f];
    }
    __syncthreads();
    int lane = threadIdx.x & 63, wv = threadIdx.x >> 6;
    int plen = p_lens[b];
    for (int j = wv; j < AA; j += 2) {
        float acc = 0.f;
        int pe = p + j;
        if (pe < PP) {
            const float* ev = endv + (size_t)(pe * BB + b) * FF;
            for (int f = lane; f < FF; f += 64)
                acc += fmaxf(ss[f] + ev[f], 0.f) * wa[f];
        } else {
            for (int f = lane; f < FF; f += 64)
                acc += fmaxf(ss[f], 0.f) * wa[f];
        }
        #pragma unroll
        for (int off = 32; off; off >>= 1) acc += __shfl_down(acc, off);
        if (lane == 0) {
            float v = (pe < plen) ? acc : 0.f;
            final_[(size_t)b * (PP * AA) + p * AA + j] = v;
        }
    }
}

// ---------------------------------------------------------------------------
__global__ void log_softmax_rows(float* __restrict__ out,
                                 const float* __restrict__ final_, int n) {
    int b = blockIdx.x;
    const float* row = final_ + (size_t)b * n;
    __shared__ float red[256];
    float m = -INFINITY;
    for (int i = threadIdx.x; i < n; i += 256) m = fmaxf(m, row[i]);
    red[threadIdx.x] = m;
    __syncthreads();
    for (int s = 128; s; s >>= 1) {
        if (threadIdx.x < s) red[threadIdx.x] = fmaxf(red[threadIdx.x], red[threadIdx.x + s]);
        __syncthreads();
    }
    m = red[0];
    __syncthreads();
    float sum = 0.f;
    for (int i = threadIdx.x; i < n; i += 256) sum += expf(row[i] - m);
    red[threadIdx.x] = sum;
    __syncthreads();
    for (int s = 128; s; s >>= 1) {
        if (threadIdx.x < s) red[threadIdx.x] += red[threadIdx.x + s];
        __syncthreads();
    }
    float lse = m + logf(red[0]);
    for (int i = threadIdx.x; i < n; i += 256) out[(size_t)b * n + i] = row[i] - lse;
}

// ---------------------------------------------------------------------------
extern "C" void kernel_launch(void* const* d_in, const int* in_sizes, int n_in,
                              void* d_out, int out_size, void* d_ws, size_t ws_size,
                              hipStream_t stream) {
    (void)in_sizes; (void)n_in; (void)out_size; (void)ws_size;
    const int*   p_tok  = (const int*)d_in[0];
    const int*   q_tok  = (const int*)d_in[1];
    const float* p_mask = (const float*)d_in[2];
    const float* q_mask = (const float*)d_in[3];
    const int*   p_lens = (const int*)d_in[4];
    const float* embed   = (const float*)d_in[6];
    const float* w_align = (const float*)d_in[7];
    const float* b_align = (const float*)d_in[8];
    const float* w_ih    = (const float*)d_in[9];    // [2,2,900,600]
    const float* w_hh    = (const float*)d_in[10];   // [2,2,900,300]
    const float* b_ih    = (const float*)d_in[11];   // [2,2,900]
    const float* b_hh    = (const float*)d_in[12];   // [2,2,900]
    const float* w_stt   = (const float*)d_in[13];
    const float* b_stt   = (const float*)d_in[14];
    const float* w_end   = (const float*)d_in[15];
    const float* b_end   = (const float*)d_in[16];
    const float* w_a     = (const float*)d_in[17];
    float* out = (float*)d_out;
    float* ws = (float*)d_ws;

    // Workspace layout (float units; all offsets multiples of 4 -> 16B align)
    size_t off = 0;
    ushort_t* p_embBF = (ushort_t*)(ws + off); off += 1945600;  // 12800x304
    ushort_t* q_embBF = (ushort_t*)(ws + off); off += 145920;   // 960x304
    float* ff_p  = ws + off;  off += (size_t)12800 * 300;
    float* ff_q  = ws + off;  off += (size_t)960 * 300;
    float* scores= ws + off;  off += (size_t)BB * PP * QQ;
    ushort_t* x0BF = (ushort_t*)(ws + off); off += 3891200;     // 12800x608
    ushort_t* x1BF = (ushort_t*)(ws + off); off += 3891200;     // 12800x608
    float* xp_f  = ws + off;  off += (size_t)400 * 32 * 900;
    float* xp_b  = ws + off;  off += (size_t)400 * 32 * 900;
    ushort_t* wihBF   = (ushort_t*)(ws + off); off += 1094400;  // 4x900x608
    ushort_t* walignBF= (ushort_t*)(ws + off); off += 45600;    // 300x304
    ushort_t* wsttBF  = (ushort_t*)(ws + off); off += 91200;    // 300x608
    ushort_t* wendBF  = (ushort_t*)(ws + off); off += 91200;    // 300x608
    ushort_t* whhBF   = (ushort_t*)(ws + off); off += 540000;   // 4x900x300
    uint_t* hbuf = (uint_t*)(ws + off); off += HBUF_DWORDS;
    float* sttb  = xp_f;                        // alias (xp dead by then)
    float* endb  = xp_f + (size_t)12800 * 300;
    float* finalb= scores;

    const int M = PP * BB;      // 12800
    const int Mq = QQ * BB;     // 960

    // weight conversions (bf16, K padded)
    convert_whh_bf16<<<(4 * 900 * 300 + 255) / 256, 256, 0, stream>>>(w_hh, whhBF);
    for (int ld = 0; ld < 4; ld++)
        convert_pad_bf16<<<(900 * 608 + 255) / 256, 256, 0, stream>>>(
            w_ih + (size_t)ld * 900 * 600, wihBF + (size_t)ld * 900 * 608,
            900, 600, 608);
    convert_pad_bf16<<<(300 * 304 + 255) / 256, 256, 0, stream>>>(
        w_align, walignBF, 300, 300, 304);
    convert_pad_bf16<<<(300 * 608 + 255) / 256, 256, 0, stream>>>(
        w_stt, wsttBF, 300, 600, 608);
    convert_pad_bf16<<<(300 * 608 + 255) / 256, 256, 0, stream>>>(
        w_end, wendBF, 300, 600, 608);

    // zero x0BF/x1BF (pads must be 0 for the K-padded GEMMs) + packet ring
    hipMemsetAsync(x0BF, 0, (size_t)12800 * 608 * 2, stream);
    hipMemsetAsync(x1BF, 0, (size_t)12800 * 608 * 2, stream);
    hipMemsetAsync(hbuf, 0, (size_t)HBUF_DWORDS * 4, stream);

    // 1. embedding gathers (bf16, padded)
    gather_embed_bf<<<(M * 304 + 255) / 256, 256, 0, stream>>>(p_tok, embed, p_embBF, M);
    gather_embed_bf<<<(Mq * 304 + 255) / 256, 256, 0, stream>>>(q_tok, embed, q_embBF, Mq);

    // 2. aligned-attention projections (relu) — MFMA bf16
    gemm_bf16_nt<<<dim3(5, 200), 256, 0, stream>>>(
        p_embBF, walignBF, b_align, ff_p, M, 300, 304, 1);
    gemm_bf16_nt<<<dim3(5, 15), 256, 0, stream>>>(
        q_embBF, walignBF, b_align, ff_q, Mq, 300, 304, 1);

    // 3. scores + softmax over q
    scores_softmax<<<PP * BB, 64, 0, stream>>>(ff_p, ff_q, p_mask, q_mask, scores);

    // 4. q_align + concat -> x0BF (bf16, stride 608)
    align_concat_bf<<<PP * BB, 256, 0, stream>>>(scores, q_embBF, p_embBF, x0BF);

    // 5. BiGRU, 2 layers: MFMA xp GEMMs + persistent MFMA recurrence
    for (int l = 0; l < LL; l++) {
        const ushort_t* xin = (l == 0) ? x0BF : x1BF;
        ushort_t* xout = (l == 0) ? x1BF : x0BF;
        gemm_bf16_nt<<<dim3(15, 200), 256, 0, stream>>>(
            xin, wihBF + (size_t)(l * 2 + 0) * 900 * 608,
            b_ih + (l * 2 + 0) * 900, xp_f, M, 900, 608, 0);
        gemm_bf16_nt<<<dim3(15, 200), 256, 0, stream>>>(
            xin, wihBF + (size_t)(l * 2 + 1) * 900 * 608,
            b_ih + (l * 2 + 1) * 900, xp_b, M, 900, 608, 0);
        gru_layer<<<2 * GRP, 512, 0, stream>>>(
            xp_f,
            whhBF + (size_t)l * 2 * 270000,
            b_hh + (size_t)l * 2 * 900,
            hbuf, l, xout);
    }

    // 6. stt / end projections (relu) from layer-2 output (x0BF)
    gemm_bf16_nt<<<dim3(5, 200), 256, 0, stream>>>(
        x0BF, wsttBF, b_stt, sttb, M, 300, 608, 1);
    gemm_bf16_nt<<<dim3(5, 200), 256, 0, stream>>>(
        x0BF, wendBF, b_end, endb, M, 300, 608, 1);

    // 7. span scores
    span_score<<<PP * BB, 128, 0, stream>>>(sttb, endb, w_a, p_lens, finalb);

    // 8. log-softmax rows -> out
    log_softmax_rows<<<BB, 256, 0, stream>>>(out, finalb, PP * AA);
}

// Round 11
// 2911.663 us; speedup vs baseline: 1.0070x; 1.0070x over previous
//
#include <hip/hip_runtime.h>
#include <hip/hip_bf16.h>
#include <math.h>

// Problem dims
#define PP 400
#define QQ 30
#define BB 32
#define EE 300
#define HH 300
#define FF 300
#define AA 30
#define LL 2

typedef unsigned short ushort_t;
typedef unsigned int uint_t;
typedef __attribute__((ext_vector_type(8))) short short8;
typedef __attribute__((ext_vector_type(16))) float floatx16;
typedef __attribute__((ext_vector_type(4))) uint_t uintx4;

__device__ __forceinline__ uint_t f2bf(float f) {
    uint_t u = __float_as_uint(f);
    return (u + 0x7fffu + ((u >> 16) & 1u)) >> 16;
}
__device__ __forceinline__ float bf2f(ushort_t v) {
    return __uint_as_float(((uint_t)v) << 16);
}

// fast transcendentals (v_exp_f32 / v_rcp_f32; rel err ~1e-6 << bf16's 4e-3)
__device__ __forceinline__ float fast_sigmoid(float x) {
    float e = __builtin_amdgcn_exp2f(x * -1.44269504f);
    return __builtin_amdgcn_rcpf(1.f + e);
}
__device__ __forceinline__ float fast_tanh(float x) {
    float xc = fminf(15.f, fmaxf(-15.f, x));
    float e = __builtin_amdgcn_exp2f(xc * 2.88539008f);   // e^(2x)
    return (e - 1.f) * __builtin_amdgcn_rcpf(e + 1.f);
}

// ---------------------------------------------------------------------------
// Embedding gather -> bf16 with K padded 300->304 (pad zeroed)
__global__ void gather_embed_bf(const int* __restrict__ tok,
                                const float* __restrict__ embed,
                                ushort_t* __restrict__ out, int n_tok) {
    int i = blockIdx.x * blockDim.x + threadIdx.x;
    int n = n_tok * 304;
    if (i >= n) return;
    int row = i / 304, e = i - row * 304;
    out[i] = (e < EE) ? (ushort_t)f2bf(embed[(size_t)tok[row] * EE + e]) : 0;
}

// fp32 [R][K] -> bf16 [R][KP], zero pad
__global__ void convert_pad_bf16(const float* __restrict__ src,
                                 ushort_t* __restrict__ dst,
                                 int R, int K, int KP) {
    int i = blockIdx.x * blockDim.x + threadIdx.x;
    if (i >= R * KP) return;
    int r = i / KP, k = i - r * KP;
    dst[i] = (k < K) ? (ushort_t)f2bf(src[(size_t)r * K + k]) : 0;
}

// ---------------------------------------------------------------------------
// MFMA bf16 GEMM: C[M,N] = A[M,KP] @ B[N,KP]^T + bias[N], optional relu.
__global__ __launch_bounds__(256) void gemm_bf16_nt(
        const ushort_t* __restrict__ A, const ushort_t* __restrict__ B,
        const float* __restrict__ bias, float* __restrict__ C,
        int M, int N, int KP, int relu) {
    __shared__ __align__(16) ushort_t As[64][16];
    __shared__ __align__(16) ushort_t Bs[64][16];
    int tid = threadIdx.x;
    int m0 = blockIdx.y * 64, n0 = blockIdx.x * 64;
    int lane = tid & 63, wv = tid >> 6;
    int wm = wv >> 1, wn = wv & 1;
    int tile = tid >> 7;
    int trow = (tid & 127) >> 1;
    int tkof = (tid & 1) * 8;
    floatx16 acc;
    #pragma unroll
    for (int r = 0; r < 16; r++) acc[r] = 0.f;

    for (int k0 = 0; k0 < KP; k0 += 16) {
        short8 v;
        if (tile == 0) {
            v = *(const short8*)(A + (size_t)(m0 + trow) * KP + k0 + tkof);
        } else {
            int br = n0 + trow;
            if (br < N)
                v = *(const short8*)(B + (size_t)br * KP + k0 + tkof);
            else
                v = short8(0);
        }
        __syncthreads();
        if (tile == 0) *(short8*)&As[trow][tkof] = v;
        else           *(short8*)&Bs[trow][tkof] = v;
        __syncthreads();
        short8 af = *(const short8*)&As[wm * 32 + (lane & 31)][(lane >> 5) * 8];
        short8 bf = *(const short8*)&Bs[wn * 32 + (lane & 31)][(lane >> 5) * 8];
        acc = __builtin_amdgcn_mfma_f32_32x32x16_bf16(af, bf, acc, 0, 0, 0);
    }
    int col = n0 + wn * 32 + (lane & 31);
    if (col < N) {
        float bv = bias[col];
        int rbase = m0 + wm * 32 + 4 * (lane >> 5);
        #pragma unroll
        for (int r = 0; r < 16; r++) {
            int row = rbase + (r & 3) + 8 * (r >> 2);
            float v = acc[r] + bv;
            if (relu) v = fmaxf(v, 0.f);
            C[(size_t)row * N + col] = v;
        }
    }
}

// ---------------------------------------------------------------------------
__global__ void scores_softmax(const float* __restrict__ ffp,
                               const float* __restrict__ ffq,
                               const float* __restrict__ p_mask,
                               const float* __restrict__ q_mask,
                               float* __restrict__ weights) {
    int blk = blockIdx.x;          // p*BB + b
    int p = blk / BB, b = blk - p * BB;
    __shared__ float fp[FF];
    __shared__ float sq[QQ];
    for (int f = threadIdx.x; f < FF; f += blockDim.x)
        fp[f] = ffp[(size_t)(p * BB + b) * FF + f];
    __syncthreads();
    int q = threadIdx.x;
    if (q < QQ) {
        const float* fq = ffq + (size_t)(q * BB + b) * FF;
        float s = 0.f;
        for (int f = 0; f < FF; f++) s += fp[f] * fq[f];
        s *= p_mask[p * BB + b] * q_mask[q * BB + b];
        sq[q] = s;
    }
    __syncthreads();
    if (q < QQ) {
        float m = -INFINITY;
        for (int k = 0; k < QQ; k++) m = fmaxf(m, sq[k]);
        float sum = 0.f;
        for (int k = 0; k < QQ; k++) sum += expf(sq[k] - m);
        weights[(size_t)b * PP * QQ + p * QQ + q] = expf(sq[q] - m) / sum;
    }
}

// ---------------------------------------------------------------------------
__global__ void align_concat_bf(const float* __restrict__ weights,
                                const ushort_t* __restrict__ q_embBF,
                                const ushort_t* __restrict__ p_embBF,
                                ushort_t* __restrict__ x0BF) {
    int blk = blockIdx.x;          // p*BB + b
    int p = blk / BB, b = blk - p * BB;
    __shared__ float w[QQ];
    if (threadIdx.x < QQ)
        w[threadIdx.x] = weights[(size_t)b * PP * QQ + p * QQ + threadIdx.x];
    __syncthreads();
    size_t obase = (size_t)(p * BB + b) * 608;
    for (int e = threadIdx.x; e < EE; e += blockDim.x) {
        float acc = 0.f;
        for (int q = 0; q < QQ; q++)
            acc += w[q] * bf2f(q_embBF[(size_t)(q * BB + b) * 304 + e]);
        x0BF[obase + e] = p_embBF[(size_t)(p * BB + b) * 304 + e];
        x0BF[obase + EE + e] = (ushort_t)f2bf(acc);
    }
}

// ---------------------------------------------------------------------------
// w_hh fp32 [4][900][300] -> bf16 (RNE) same layout (GRU A-fragments)
__global__ void convert_whh_bf16(const float* __restrict__ w,
                                 ushort_t* __restrict__ o) {
    int i = blockIdx.x * blockDim.x + threadIdx.x;
    if (i >= 4 * 900 * 300) return;
    o[i] = (ushort_t)f2bf(w[i]);
}

// ---------------------------------------------------------------------------
// Persistent BiGRU layer, MFMA recurrence, tagged-packet handoff.
// R19 = R17 verbatim (measured session best: 2912 µs; R18's out-store
// reorder was neutral-negative and is reverted). Structure: R12 lineage
// (graded poll waits + fast gates + store drain) + R17's poll-first
// ordering (xp prefetch after the poll; its HBM latency hides under the
// MFMA phase instead of polluting the poll FIFO).
// Step ≈ 6530cy: MFMA 918 + gates 250 + publish drain ~RT + LLC visibility
// ~RT + detection ~1.5RT + barriers/skew — all remaining terms pinned to
// the ~1400-2000cy cross-CU visibility RT (R14 calibration). Alternatives
// falsified on HW: sc0-scope (R9/R10), flag handoff (R14), batch-split
// (R15/R16), poll specialization (R13).
#define GRP 5
#define RSLOT 8
#define NPKT 1600            // per dir: 300 j * 32 b / 6
#define HBUF_DWORDS (2 * RSLOT * NPKT * 4)

__global__ __launch_bounds__(512, 1) void gru_layer(
        const float* __restrict__ xp_all, // [2 dir][400][32][900] contiguous
        const ushort_t* __restrict__ wbf, // [2 dir][900][300] bf16, this layer
        const float* __restrict__ bhh,    // [2 dir][900], this layer
        uint_t* __restrict__ hbuf,        // shared packet ring (zeroed)
        int layer,
        ushort_t* __restrict__ out) {     // [400][32][608] bf16
    int dir = blockIdx.x / GRP;
    int bi  = blockIdx.x - dir * GRP;
    int j0  = bi * 60;
    const float* xp = xp_all + (size_t)dir * (400 * 32 * 900);
    int tid = threadIdx.x;
    int lane = tid & 63;
    int wv = tid >> 6;                 // wave 0..7 (0-5 do MFMA)
    uint_t* hb_dir = hbuf + (size_t)dir * (RSLOT * NPKT * 4);

    __shared__ __align__(16) ushort_t sh2[32][312]; // h bf16 [batch][k]
    __shared__ float sgh[180][33];    // gh f32 [block row][batch]

    for (int i = tid; i < 32 * 156; i += 512) ((uint_t*)sh2)[i] = 0u;

    // A-fragments resident: wave wv owns block rows wv*32 .. +31
    short8 afrag[19];
    if (wv < 6) {
        int m = lane & 31, half = lane >> 5;
        int r = wv * 32 + m;
        if (r < 180) {
            int g = r / 60, jl = r - g * 60;
            const ushort_t* wrow = wbf + (size_t)dir * 270000
                                   + (size_t)(g * 300 + j0 + jl) * 300;
            for (int c = 0; c < 19; c++) {
                int k0 = c * 16 + half * 8;
                short8 f;
                #pragma unroll
                for (int e = 0; e < 8; e++) {
                    int k = k0 + e;
                    f[e] = (short)((k < 300) ? wrow[k] : (ushort_t)0);
                }
                afrag[c] = f;
            }
        } else {
            #pragma unroll
            for (int c = 0; c < 19; c++) afrag[c] = short8(0);
        }
    }

    // poll assignment: pad to exactly 4 packets/thread (uniform vmcnt
    // immediates); own block's packets skipped (producers write them
    // straight into next-step sh2). Every thread has >=2 real packets.
    int pollP[4], polldst[4];
    int npoll = 0;
    int ownlo = bi * 320;
    for (int k = 0; k < 4; k++) {
        int P = tid + 512 * k;
        if (P < NPKT && (P < ownlo || P >= ownlo + 320)) {
            pollP[npoll] = P;
            int pbi = P / 320, rem = P - pbi * 320;
            int pb = rem / 10, pq = rem - pb * 10;
            polldst[npoll] = pb * 156 + pbi * 30 + 3 * pq;
            npoll++;
        }
    }
    for (int k = npoll; k < 4; k++) { pollP[k] = pollP[0]; polldst[k] = polldst[0]; }

    // gate ownership (t<320): b=t/10, q=t%10 -> h[j0+6q..+5] of batch b
    int gb = tid / 10, gq = tid - (tid / 10) * 10;
    float hprev[6] = {0.f, 0.f, 0.f, 0.f, 0.f, 0.f};
    float br_[6], bz_[6], bn_[6];
    if (tid < 320) {
        #pragma unroll
        for (int i = 0; i < 6; i++) {
            int jj = j0 + gq * 6 + i;
            br_[i] = bhh[dir * 900 + jj];
            bz_[i] = bhh[dir * 900 + 300 + jj];
            bn_[i] = bhh[dir * 900 + 600 + jj];
        }
    }
    __syncthreads();

    for (int s = 0; s < PP; s++) {
        int te = dir ? (PP - 1 - s) : s;
        // poll tagged packets for h(s); unpack into sh2 (FIFO is clean:
        // only prev-step's out store is ahead of the poll loads)
        if (s > 0) {
            uint_t want = (uint_t)(layer * 1024 + s);
            const uint_t* base = hb_dir + (size_t)(s & 7) * (NPKT * 4);
            const uint_t* a0p = base + (size_t)pollP[0] * 4;
            const uint_t* a1p = base + (size_t)pollP[1] * 4;
            const uint_t* a2p = base + (size_t)pollP[2] * 4;
            const uint_t* a3p = base + (size_t)pollP[3] * 4;
            int pend = (1 << npoll) - 1;
            uint_t* shdw = (uint_t*)sh2;
            while (pend) {
                uintx4 v0, v1, v2, v3;
                asm volatile("global_load_dwordx4 %0, %1, off sc0 sc1"
                             : "=&v"(v0) : "v"(a0p) : "memory");
                asm volatile("global_load_dwordx4 %0, %1, off sc0 sc1"
                             : "=&v"(v1) : "v"(a1p) : "memory");
                asm volatile("global_load_dwordx4 %0, %1, off sc0 sc1"
                             : "=&v"(v2) : "v"(a2p) : "memory");
                asm volatile("global_load_dwordx4 %0, %1, off sc0 sc1"
                             : "=&v"(v3) : "v"(a3p) : "memory");
                asm volatile("s_waitcnt vmcnt(3)" ::: "memory");
                __builtin_amdgcn_sched_barrier(0);
                if ((pend & 1) && v0.w == want) {
                    pend &= ~1;
                    shdw[polldst[0] + 0] = v0.x;
                    shdw[polldst[0] + 1] = v0.y;
                    shdw[polldst[0] + 2] = v0.z;
                }
                asm volatile("s_waitcnt vmcnt(2)" ::: "memory");
                __builtin_amdgcn_sched_barrier(0);
                if ((pend & 2) && v1.w == want) {
                    pend &= ~2;
                    shdw[polldst[1] + 0] = v1.x;
                    shdw[polldst[1] + 1] = v1.y;
                    shdw[polldst[1] + 2] = v1.z;
                }
                asm volatile("s_waitcnt vmcnt(1)" ::: "memory");
                __builtin_amdgcn_sched_barrier(0);
                if ((pend & 4) && v2.w == want) {
                    pend &= ~4;
                    shdw[polldst[2] + 0] = v2.x;
                    shdw[polldst[2] + 1] = v2.y;
                    shdw[polldst[2] + 2] = v2.z;
                }
                asm volatile("s_waitcnt vmcnt(0)" ::: "memory");
                __builtin_amdgcn_sched_barrier(0);
                if ((pend & 8) && v3.w == want) {
                    pend &= ~8;
                    shdw[polldst[3] + 0] = v3.x;
                    shdw[polldst[3] + 1] = v3.y;
                    shdw[polldst[3] + 2] = v3.z;
                }
            }
        }
        // xp prefetch — AFTER the poll (R17): latency hides under MFMA phase
        float xrv[6], xzv[6], xnv[6];
        if (tid < 320) {
            const float* base = xp + ((size_t)te * 32 + gb) * 900 + j0 + gq * 6;
            #pragma unroll
            for (int u = 0; u < 3; u++) {
                *(float2*)&xrv[2 * u] = *(const float2*)(base + 2 * u);
                *(float2*)&xzv[2 * u] = *(const float2*)(base + 300 + 2 * u);
                *(float2*)&xnv[2 * u] = *(const float2*)(base + 600 + 2 * u);
            }
        }
        __syncthreads();                       // B1: sh2 complete
        // MFMA: waves 0-5, A resident, B from LDS; 2 independent acc chains
        if (wv < 6) {
            floatx16 a0, a1;
            #pragma unroll
            for (int r = 0; r < 16; r++) { a0[r] = 0.f; a1[r] = 0.f; }
            int n = lane & 31, half = lane >> 5;
            #pragma unroll
            for (int c = 0; c < 18; c += 2) {
                short8 bf0 = *(const short8*)&sh2[n][c * 16 + half * 8];
                a0 = __builtin_amdgcn_mfma_f32_32x32x16_bf16(
                    afrag[c], bf0, a0, 0, 0, 0);
                short8 bf1 = *(const short8*)&sh2[n][(c + 1) * 16 + half * 8];
                a1 = __builtin_amdgcn_mfma_f32_32x32x16_bf16(
                    afrag[c + 1], bf1, a1, 0, 0, 0);
            }
            {
                short8 bf0 = *(const short8*)&sh2[n][18 * 16 + half * 8];
                a0 = __builtin_amdgcn_mfma_f32_32x32x16_bf16(
                    afrag[18], bf0, a0, 0, 0, 0);
            }
            int col = lane & 31, rbase = 4 * (lane >> 5);
            #pragma unroll
            for (int r = 0; r < 16; r++) {
                int row = (r & 3) + 8 * (r >> 2) + rbase;
                int grow = wv * 32 + row;
                if (grow < 180) sgh[grow][col] = a0[r] + a1[r];
            }
        }
        __syncthreads();                       // B2: sgh complete
        // gates from registers; publish packet straight from registers
        if (tid < 320) {
            float houts[6];
            uint_t pk[3];
            #pragma unroll
            for (int i = 0; i < 6; i++) {
                int jl = gq * 6 + i;
                float ghr = sgh[jl][gb];
                float ghz = sgh[60 + jl][gb];
                float ghn = sgh[120 + jl][gb];
                float r = fast_sigmoid(xrv[i] + ghr + br_[i]);
                float z = fast_sigmoid(xzv[i] + ghz + bz_[i]);
                float n = fast_tanh(xnv[i] + r * (ghn + bn_[i]));
                float h = (1.f - z) * n + z * hprev[i];
                hprev[i] = h;
                houts[i] = h;
            }
            #pragma unroll
            for (int u = 0; u < 3; u++)
                pk[u] = f2bf(houts[2 * u]) | (f2bf(houts[2 * u + 1]) << 16);
            uintx4 pkt;
            pkt.x = pk[0]; pkt.y = pk[1]; pkt.z = pk[2];
            pkt.w = (uint_t)(layer * 1024 + s + 1);
            uint_t* pa = hb_dir + (size_t)((s + 1) & 7) * (NPKT * 4)
                         + (size_t)(bi * 320 + tid) * 4;
            asm volatile("global_store_dwordx4 %0, %1, off sc0 sc1"
                         :: "v"(pa), "v"(pkt) : "memory");
            // force the packet store to the coherence point NOW (R12):
            // earliest possible start of remote visibility.
            asm volatile("s_waitcnt vmcnt(0)" ::: "memory");
            __builtin_amdgcn_sched_barrier(0);
            // own-block h for next step goes straight into LDS (no self RT).
            // Safe: MFMA reads of sh2 for step s finished before B2; pollers
            // of step s+1 only write remote dsts (disjoint).
            {
                uint_t* shdw2 = (uint_t*)sh2;
                int own = gb * 156 + bi * 30 + 3 * gq;
                shdw2[own + 0] = pk[0];
                shdw2[own + 1] = pk[1];
                shdw2[own + 2] = pk[2];
            }
            // bf16 out store (off the handoff critical path)
            uint_t* ob = (uint_t*)(out + ((size_t)te * 32 + gb) * 608
                                   + dir * 300 + j0 + gq * 6);
            ob[0] = pk[0]; ob[1] = pk[1]; ob[2] = pk[2];
        }
    }
}

// ---------------------------------------------------------------------------
__global__ void span_score(const float* __restrict__ stt,
                           const float* __restrict__ endv,
                           const float* __restrict__ w_a,
                           const int* __restrict__ p_lens,
                           float* __restrict__ final_) {
    int blk = blockIdx.x;          // p*BB + b
    int p = blk / BB, b = blk - p * BB;
    __shared__ float ss[FF];
    __shared__ float wa[FF];
    for (int f = threadIdx.x; f < FF; f += blockDim.x) {
        ss[f] = stt[(size_t)(p * BB + b) * FF + f];
        wa[f] = w_a[f];
    }
    __syncthreads();
    int lane = threadIdx.x & 63, wv = threadIdx.x >> 6;
    int plen = p_lens[b];
    for (int j = wv; j < AA; j += 2) {
        float acc = 0.f;
        int pe = p + j;
        if (pe < PP) {
            const float* ev = endv + (size_t)(pe * BB + b) * FF;
            for (int f = lane; f < FF; f += 64)
                acc += fmaxf(ss[f] + ev[f], 0.f) * wa[f];
        } else {
            for (int f = lane; f < FF; f += 64)
                acc += fmaxf(ss[f], 0.f) * wa[f];
        }
        #pragma unroll
        for (int off = 32; off; off >>= 1) acc += __shfl_down(acc, off);
        if (lane == 0) {
            float v = (pe < plen) ? acc : 0.f;
            final_[(size_t)b * (PP * AA) + p * AA + j] = v;
        }
    }
}

// ---------------------------------------------------------------------------
__global__ void log_softmax_rows(float* __restrict__ out,
                                 const float* __restrict__ final_, int n) {
    int b = blockIdx.x;
    const float* row = final_ + (size_t)b * n;
    __shared__ float red[256];
    float m = -INFINITY;
    for (int i = threadIdx.x; i < n; i += 256) m = fmaxf(m, row[i]);
    red[threadIdx.x] = m;
    __syncthreads();
    for (int s = 128; s; s >>= 1) {
        if (threadIdx.x < s) red[threadIdx.x] = fmaxf(red[threadIdx.x], red[threadIdx.x + s]);
        __syncthreads();
    }
    m = red[0];
    __syncthreads();
    float sum = 0.f;
    for (int i = threadIdx.x; i < n; i += 256) sum += expf(row[i] - m);
    red[threadIdx.x] = sum;
    __syncthreads();
    for (int s = 128; s; s >>= 1) {
        if (threadIdx.x < s) red[threadIdx.x] += red[threadIdx.x + s];
        __syncthreads();
    }
    float lse = m + logf(red[0]);
    for (int i = threadIdx.x; i < n; i += 256) out[(size_t)b * n + i] = row[i] - lse;
}

// ---------------------------------------------------------------------------
extern "C" void kernel_launch(void* const* d_in, const int* in_sizes, int n_in,
                              void* d_out, int out_size, void* d_ws, size_t ws_size,
                              hipStream_t stream) {
    (void)in_sizes; (void)n_in; (void)out_size; (void)ws_size;
    const int*   p_tok  = (const int*)d_in[0];
    const int*   q_tok  = (const int*)d_in[1];
    const float* p_mask = (const float*)d_in[2];
    const float* q_mask = (const float*)d_in[3];
    const int*   p_lens = (const int*)d_in[4];
    const float* embed   = (const float*)d_in[6];
    const float* w_align = (const float*)d_in[7];
    const float* b_align = (const float*)d_in[8];
    const float* w_ih    = (const float*)d_in[9];    // [2,2,900,600]
    const float* w_hh    = (const float*)d_in[10];   // [2,2,900,300]
    const float* b_ih    = (const float*)d_in[11];   // [2,2,900]
    const float* b_hh    = (const float*)d_in[12];   // [2,2,900]
    const float* w_stt   = (const float*)d_in[13];
    const float* b_stt   = (const float*)d_in[14];
    const float* w_end   = (const float*)d_in[15];
    const float* b_end   = (const float*)d_in[16];
    const float* w_a     = (const float*)d_in[17];
    float* out = (float*)d_out;
    float* ws = (float*)d_ws;

    // Workspace layout (float units; all offsets multiples of 4 -> 16B align)
    size_t off = 0;
    ushort_t* p_embBF = (ushort_t*)(ws + off); off += 1945600;  // 12800x304
    ushort_t* q_embBF = (ushort_t*)(ws + off); off += 145920;   // 960x304
    float* ff_p  = ws + off;  off += (size_t)12800 * 300;
    float* ff_q  = ws + off;  off += (size_t)960 * 300;
    float* scores= ws + off;  off += (size_t)BB * PP * QQ;
    ushort_t* x0BF = (ushort_t*)(ws + off); off += 3891200;     // 12800x608
    ushort_t* x1BF = (ushort_t*)(ws + off); off += 3891200;     // 12800x608
    float* xp_f  = ws + off;  off += (size_t)400 * 32 * 900;
    float* xp_b  = ws + off;  off += (size_t)400 * 32 * 900;
    ushort_t* wihBF   = (ushort_t*)(ws + off); off += 1094400;  // 4x900x608
    ushort_t* walignBF= (ushort_t*)(ws + off); off += 45600;    // 300x304
    ushort_t* wsttBF  = (ushort_t*)(ws + off); off += 91200;    // 300x608
    ushort_t* wendBF  = (ushort_t*)(ws + off); off += 91200;    // 300x608
    ushort_t* whhBF   = (ushort_t*)(ws + off); off += 540000;   // 4x900x300
    uint_t* hbuf = (uint_t*)(ws + off); off += HBUF_DWORDS;
    float* sttb  = xp_f;                        // alias (xp dead by then)
    float* endb  = xp_f + (size_t)12800 * 300;
    float* finalb= scores;

    const int M = PP * BB;      // 12800
    const int Mq = QQ * BB;     // 960

    // weight conversions (bf16, K padded)
    convert_whh_bf16<<<(4 * 900 * 300 + 255) / 256, 256, 0, stream>>>(w_hh, whhBF);
    for (int ld = 0; ld < 4; ld++)
        convert_pad_bf16<<<(900 * 608 + 255) / 256, 256, 0, stream>>>(
            w_ih + (size_t)ld * 900 * 600, wihBF + (size_t)ld * 900 * 608,
            900, 600, 608);
    convert_pad_bf16<<<(300 * 304 + 255) / 256, 256, 0, stream>>>(
        w_align, walignBF, 300, 300, 304);
    convert_pad_bf16<<<(300 * 608 + 255) / 256, 256, 0, stream>>>(
        w_stt, wsttBF, 300, 600, 608);
    convert_pad_bf16<<<(300 * 608 + 255) / 256, 256, 0, stream>>>(
        w_end, wendBF, 300, 600, 608);

    // zero x0BF/x1BF (pads must be 0 for the K-padded GEMMs) + packet ring
    hipMemsetAsync(x0BF, 0, (size_t)12800 * 608 * 2, stream);
    hipMemsetAsync(x1BF, 0, (size_t)12800 * 608 * 2, stream);
    hipMemsetAsync(hbuf, 0, (size_t)HBUF_DWORDS * 4, stream);

    // 1. embedding gathers (bf16, padded)
    gather_embed_bf<<<(M * 304 + 255) / 256, 256, 0, stream>>>(p_tok, embed, p_embBF, M);
    gather_embed_bf<<<(Mq * 304 + 255) / 256, 256, 0, stream>>>(q_tok, embed, q_embBF, Mq);

    // 2. aligned-attention projections (relu) — MFMA bf16
    gemm_bf16_nt<<<dim3(5, 200), 256, 0, stream>>>(
        p_embBF, walignBF, b_align, ff_p, M, 300, 304, 1);
    gemm_bf16_nt<<<dim3(5, 15), 256, 0, stream>>>(
        q_embBF, walignBF, b_align, ff_q, Mq, 300, 304, 1);

    // 3. scores + softmax over q
    scores_softmax<<<PP * BB, 64, 0, stream>>>(ff_p, ff_q, p_mask, q_mask, scores);

    // 4. q_align + concat -> x0BF (bf16, stride 608)
    align_concat_bf<<<PP * BB, 256, 0, stream>>>(scores, q_embBF, p_embBF, x0BF);

    // 5. BiGRU, 2 layers: MFMA xp GEMMs + persistent MFMA recurrence
    for (int l = 0; l < LL; l++) {
        const ushort_t* xin = (l == 0) ? x0BF : x1BF;
        ushort_t* xout = (l == 0) ? x1BF : x0BF;
        gemm_bf16_nt<<<dim3(15, 200), 256, 0, stream>>>(
            xin, wihBF + (size_t)(l * 2 + 0) * 900 * 608,
            b_ih + (l * 2 + 0) * 900, xp_f, M, 900, 608, 0);
        gemm_bf16_nt<<<dim3(15, 200), 256, 0, stream>>>(
            xin, wihBF + (size_t)(l * 2 + 1) * 900 * 608,
            b_ih + (l * 2 + 1) * 900, xp_b, M, 900, 608, 0);
        gru_layer<<<2 * GRP, 512, 0, stream>>>(
            xp_f,
            whhBF + (size_t)l * 2 * 270000,
            b_hh + (size_t)l * 2 * 900,
            hbuf, l, xout);
    }

    // 6. stt / end projections (relu) from layer-2 output (x0BF)
    gemm_bf16_nt<<<dim3(5, 200), 256, 0, stream>>>(
        x0BF, wsttBF, b_stt, sttb, M, 300, 608, 1);
    gemm_bf16_nt<<<dim3(5, 200), 256, 0, stream>>>(
        x0BF, wendBF, b_end, endb, M, 300, 608, 1);

    // 7. span scores
    span_score<<<PP * BB, 128, 0, stream>>>(sttb, endb, w_a, p_lens, finalb);

    // 8. log-softmax rows -> out
    log_softmax_rows<<<BB, 256, 0, stream>>>(out, finalb, PP * AA);
}